// Round 11
// baseline (28.987 us; speedup 1.0000x reference)
//
#include <hip/hip_runtime.h>
#include <math.h>

#define CIN   8
#define COUT  8
#define HH    16
#define NN    400
#define MM    400
#define BB    16

#define THREADS 512
#define PMAX    32      // per-m slot clamp (worst-case inside count ~31)
#define NGRP    16      // packer groups
#define MPG     25      // m's per group (NGRP*MPG = 400)
#define PPG     16      // page slots per group (worst case needed ~7)
#define NPAGES  (NGRP*PPG)   // 256
#define MAXNM   12      // max m's per page (min cnt>=5 -> <= 12)

// ws layout (floats):
//   ft[NN*CIN*BB]   : ft[n*128 + b*8 + i] = f[b][i][n]   (i contiguous)
//   lst[MM*PMAX*4]  : per slot float4 {zx, zy, bw, as_float(n)}
//   cnt[MM] (int), pg_m0[NPAGES] (int), pg_nm[NPAGES] (int)
#define WS_FT   0
#define WS_L    (NN*CIN*BB)
#define WS_CNT  (WS_L + MM*PMAX*4)
#define WS_PM0  (WS_CNT + MM)
#define WS_PNM  (WS_PM0 + NPAGES)

// EXACT inside test — must be bit-identical between list-build and counter.
__device__ __forceinline__ bool bump_inside(float zx, float zy, float& a) {
    float s = __fadd_rn(__fmul_rn(zx, zx), __fmul_rn(zy, zy));
    a = __fmul_rn(s, s);                       // ||z||^4
    return a < (1.0f / 625.0f);
}

// ---------------- kernel 1: transpose + per-m lists + counts + pages --------
__global__ __launch_bounds__(THREADS) void prep_kernel(
    const float* __restrict__ f,      // (B, CIN, NN)
    const float* __restrict__ locs,   // (MM, 2)
    const float* __restrict__ nodes,  // (NN, 2)
    const float* __restrict__ wq,     // (NN,)
    float* __restrict__ ws)
{
    const int blk = blockIdx.x;
    const int t   = threadIdx.x;

    if (blk < 100) {
        // transpose, read-coalesced: idx walks f linearly
        int idx = blk * 512 + t;              // = b*3200 + i*400 + n
        int b = idx / 3200;
        int r = idx - b * 3200;
        int i = r / 400;
        int n = r - i * 400;
        ws[WS_FT + n*128 + b*8 + i] = f[idx];
    } else if (blk < 150) {
        // inside-lists: 50 blocks x 8 waves, one m per wave
        const int lane = t & 63;
        const int w    = t >> 6;
        const int m    = (blk - 100) * 8 + w;
        const float2 y = ((const float2*)locs)[m];
        const float2* nd = (const float2*)nodes;
        float4* lst = (float4*)(ws + WS_L);
        int cnt = 0;
        for (int n0 = 0; n0 < NN; n0 += 64) {
            int n = n0 + lane;
            bool in = false;
            float zx = 0.f, zy = 0.f, bwv = 0.f;
            if (n < NN) {
                float2 x = nd[n];
                zx = y.x - x.x; zy = y.y - x.y;
                float a;
                if (bump_inside(zx, zy, a)) {
                    in = true;
                    bwv = __expf(1.0f - 1.0f/(1.0f - 625.0f*a)) * wq[n];
                }
            }
            unsigned long long msk = __ballot(in);
            int idx = cnt + __popcll(msk & ((1ull << lane) - 1ull));
            if (in && idx < PMAX)
                lst[m*PMAX + idx] = make_float4(zx, zy, bwv, __int_as_float(n));
            cnt += __popcll(msk);
        }
        if (lane >= cnt && lane < PMAX)
            lst[m*PMAX + lane] = make_float4(0.f, 0.f, 0.f, __int_as_float(0));
    } else {
        // block 150: counts (bit-identical test) + greedy page packing
        __shared__ float dx2[400], dy2[400];
        __shared__ int   scnt[400];
        if (t < 400) {
            int i = t / 20, j = t % 20;
            float zx = locs[2*i]          - nodes[2*j];          // x coords
            float zy = locs[2*(i*20) + 1] - nodes[2*(j*20) + 1]; // y coords
            dx2[t] = __fmul_rn(zx, zx);
            dy2[t] = __fmul_rn(zy, zy);
        }
        __syncthreads();
        if (t < 400) {
            int mx = t % 20, my = t / 20;
            int c = 0;
            for (int ny = 0; ny < 20; ++ny) {
                float dyv = dy2[my*20 + ny];
                for (int nx = 0; nx < 20; ++nx) {
                    float s = __fadd_rn(dx2[mx*20 + nx], dyv);
                    float a = __fmul_rn(s, s);
                    c += (a < (1.0f / 625.0f)) ? 1 : 0;
                }
            }
            c = min(c, PMAX);
            scnt[t] = c;
            ((int*)ws)[WS_CNT + t] = c;
        }
        __syncthreads();
        if (t < NGRP) {
            int* pm0 = (int*)ws + WS_PM0;
            int* pnm = (int*)ws + WS_PNM;
            const int m0g = t * MPG, mend = m0g + MPG;
            int p = t * PPG;
            int cur0 = m0g, used = 0;
            for (int m = m0g; m < mend; ++m) {
                int c = scnt[m];
                if (used + c > 64) {
                    pm0[p] = cur0; pnm[p] = m - cur0; ++p;
                    cur0 = m; used = 0;
                }
                used += c;
            }
            pm0[p] = cur0; pnm[p] = mend - cur0; ++p;
            for (; p < (t + 1) * PPG; ++p) { pm0[p] = 0; pnm[p] = 0; }
        }
    }
}

// ---------------- kernel 2: MLP eval + contraction (2 pages / block) --------
// grid = (NPAGES/2) * 8; block (pp, kg): pages 2pp, 2pp+1; o = kg.
// wave w: k = kg*8 + w -> o = kg, i = w. Each lane evaluates slotA (page A)
// and slotB (page B), reusing each W2 row register-resident for both.
__global__ __launch_bounds__(THREADS) void quadconv_kernel(
    const float* __restrict__ W1,     // (K, H, 2)
    const float* __restrict__ W2,     // (K, H, H)
    const float* __restrict__ W3,     // (K, 1, H)
    const float* __restrict__ ws,     // ft + lists + pages
    float* __restrict__ out)          // (B, COUT, MM)
{
    __shared__ float s_w2[8*256];     // [k_local][oo*16+j]
    __shared__ float s_w1[8*32];
    __shared__ float s_w3[8*16];
    __shared__ float s_kvT[2][64*10]; // [page][slot*10 + wave(i)], padded
    __shared__ float s_pp[2][64*17];  // [page][slot][b] partials, +1 pad
    __shared__ int   s_pn[2][64];
    __shared__ int   s_off[2][MAXNM + 1];
    __shared__ int   s_m0[2];

    const int t    = threadIdx.x;
    const int lane = t & 63;
    const int w    = __builtin_amdgcn_readfirstlane(t >> 6);
    const int pp   = blockIdx.x >> 3;
    const int kg   = blockIdx.x & 7;
    const int pA   = pp * 2;

    const int nmA = ((const int*)ws)[WS_PNM + pA];
    const int nmB = ((const int*)ws)[WS_PNM + pA + 1];
    // pages fill group-slots from the front and pairs are group-aligned
    // (PPG even), so nmA == 0 implies nmB == 0.
    if (nmA == 0) return;

    // ---- stage this block's 8 weight sets into LDS ----
    {
        const float4* W2v = (const float4*)(W2 + kg * 8 * 256);   // 512 float4
        ((float4*)s_w2)[t] = W2v[t];
        if (t < 64) ((float4*)s_w1)[t] = ((const float4*)(W1 + kg * 8 * 32))[t];
        if (t < 32) ((float4*)s_w3)[t] = ((const float4*)(W3 + kg * 8 * 16))[t];
    }
    // ---- parallel segment offsets: waves 0,1 scan pages A,B ----
    if (w < 2) {
        const int nm = (w == 0) ? nmA : nmB;
        const int m0 = ((const int*)ws)[WS_PM0 + pA + w];
        int c = (lane < nm) ? ((const int*)ws)[WS_CNT + m0 + lane] : 0;
        #pragma unroll
        for (int d = 1; d < 16; d <<= 1) {
            int u = __shfl_up(c, d);
            if (lane >= d) c += u;
        }
        if (lane < nm) s_off[w][lane + 1] = c;
        if (lane == 0) { s_off[w][0] = 0; s_m0[w] = m0; }
    }
    __syncthreads();

    // ---- per-lane slot resolve + list load for both pages ----
    float4 sv[2];
    int    n_id[2];
    #pragma unroll
    for (int pg = 0; pg < 2; ++pg) {
        const int nm = (pg == 0) ? nmA : nmB;
        int seg = 0;
        #pragma unroll
        for (int sgi = 1; sgi < MAXNM; ++sgi)
            seg += (sgi < nm && lane >= s_off[pg][sgi]) ? 1 : 0;
        const int used = s_off[pg][nm];   // nm==0 -> s_off[pg][0]==0
        float4 v = make_float4(0.f, 0.f, 0.f, 0.f);
        int nid = 0;
        if (lane < used) {
            const int m  = s_m0[pg] + seg;
            const int jj = lane - s_off[pg][seg];
            v = ((const float4*)(ws + WS_L))[m * PMAX + jj];
            nid = __float_as_int(v.w);
        }
        sv[pg] = v; n_id[pg] = nid;
    }
    if (w == 0) s_pn[0][lane] = n_id[0];
    if (w == 1) s_pn[1][lane] = n_id[1];

    // ---- Phase B: per-wave MLP, W2 rows register-reused across both pages --
    {
        const float* __restrict__ w1 = s_w1 + w * 32;
        const float* __restrict__ w3p = s_w3 + w * 16;
        float4 w3q[4];
        #pragma unroll
        for (int q = 0; q < 4; ++q) w3q[q] = ((const float4*)w3p)[q];
        float w3r[16] = {w3q[0].x, w3q[0].y, w3q[0].z, w3q[0].w,
                         w3q[1].x, w3q[1].y, w3q[1].z, w3q[1].w,
                         w3q[2].x, w3q[2].y, w3q[2].z, w3q[2].w,
                         w3q[3].x, w3q[3].y, w3q[3].z, w3q[3].w};

        float h1A[HH], h1B[HH];
        #pragma unroll
        for (int j = 0; j < HH; ++j) {
            float wa = w1[2*j], wb = w1[2*j + 1];
            h1A[j] = __sinf(wa * sv[0].x + wb * sv[0].y);
            h1B[j] = __sinf(wa * sv[1].x + wb * sv[1].y);
        }
        float kvA = 0.f, kvB = 0.f;
        const float4* __restrict__ w2v = (const float4*)(s_w2 + w * 256);
        #pragma unroll
        for (int oo = 0; oo < HH; ++oo) {
            float4 r0 = w2v[oo*4+0], r1 = w2v[oo*4+1],
                   r2 = w2v[oo*4+2], r3 = w2v[oo*4+3];
            float dA = r0.x*h1A[0] + r0.y*h1A[1] + r0.z*h1A[2] + r0.w*h1A[3]
                     + r1.x*h1A[4] + r1.y*h1A[5] + r1.z*h1A[6] + r1.w*h1A[7]
                     + r2.x*h1A[8] + r2.y*h1A[9] + r2.z*h1A[10]+ r2.w*h1A[11]
                     + r3.x*h1A[12]+ r3.y*h1A[13]+ r3.z*h1A[14]+ r3.w*h1A[15];
            float dB = r0.x*h1B[0] + r0.y*h1B[1] + r0.z*h1B[2] + r0.w*h1B[3]
                     + r1.x*h1B[4] + r1.y*h1B[5] + r1.z*h1B[6] + r1.w*h1B[7]
                     + r2.x*h1B[8] + r2.y*h1B[9] + r2.z*h1B[10]+ r2.w*h1B[11]
                     + r3.x*h1B[12]+ r3.y*h1B[13]+ r3.z*h1B[14]+ r3.w*h1B[15];
            kvA += w3r[oo] * __sinf(dA);
            kvB += w3r[oo] * __sinf(dB);
        }
        s_kvT[0][lane*10 + w] = kvA * sv[0].z;
        s_kvT[1][lane*10 + w] = kvB * sv[1].z;
    }
    __syncthreads();   // s_kvT + s_pn ready

    // ---- Phase C stage 1: 512 threads, partial[pg][j][b] via float4 loads --
    {
        const int j  = t >> 3;         // slot
        const int b0 = t & 7;          // handles b0 and b0+8
        #pragma unroll
        for (int pg = 0; pg < 2; ++pg) {
            const int n = s_pn[pg][j];
            const float* __restrict__ fb = ws + WS_FT + n*128;
            float4 A0 = *(const float4*)(fb + b0*8);
            float4 A1 = *(const float4*)(fb + b0*8 + 4);
            float4 B0 = *(const float4*)(fb + (b0+8)*8);
            float4 B1 = *(const float4*)(fb + (b0+8)*8 + 4);
            const float* kr = &s_kvT[pg][j*10];
            float k0 = kr[0], k1 = kr[1], k2 = kr[2], k3 = kr[3];
            float k4 = kr[4], k5 = kr[5], k6 = kr[6], k7 = kr[7];
            float pAcc = k0*A0.x + k1*A0.y + k2*A0.z + k3*A0.w
                       + k4*A1.x + k5*A1.y + k6*A1.z + k7*A1.w;
            float pBcc = k0*B0.x + k1*B0.y + k2*B0.z + k3*B0.w
                       + k4*B1.x + k5*B1.y + k6*B1.z + k7*B1.w;
            s_pp[pg][j*17 + b0]     = pAcc;
            s_pp[pg][j*17 + b0 + 8] = pBcc;
        }
    }
    __syncthreads();

    // ---- Phase C stage 2: LDS-only segmented sums, (m, b) threads ----
    #pragma unroll
    for (int pg = 0; pg < 2; ++pg) {
        const int nm = (pg == 0) ? nmA : nmB;
        if (t < nm * 16) {
            const int b    = t & 15;
            const int sidx = t >> 4;
            const int lo   = s_off[pg][sidx];
            const int hi   = s_off[pg][sidx + 1];
            float acc = 0.f;
            for (int j = lo; j < hi; ++j)
                acc += s_pp[pg][j*17 + b];
            out[b * (COUT*MM) + kg * MM + (s_m0[pg] + sidx)] = acc;
        }
    }
}

extern "C" void kernel_launch(void* const* d_in, const int* in_sizes, int n_in,
                              void* d_out, int out_size, void* d_ws, size_t ws_size,
                              hipStream_t stream) {
    const float* f     = (const float*)d_in[0];
    const float* W1    = (const float*)d_in[1];
    const float* W2    = (const float*)d_in[2];
    const float* W3    = (const float*)d_in[3];
    const float* locs  = (const float*)d_in[4];
    const float* nodes = (const float*)d_in[5];
    const float* wq    = (const float*)d_in[6];
    float* out = (float*)d_out;
    float* ws  = (float*)d_ws;

    prep_kernel<<<dim3(151), dim3(THREADS), 0, stream>>>(f, locs, nodes, wq, ws);
    quadconv_kernel<<<dim3((NPAGES/2) * 8), dim3(THREADS), 0, stream>>>(
        W1, W2, W3, ws, out);
}

// Round 12
// 25.851 us; speedup vs baseline: 1.1213x; 1.1213x over previous
//
#include <hip/hip_runtime.h>
#include <math.h>

#define CIN   8
#define COUT  8
#define HH    16
#define NN    400
#define MM    400
#define BB    16

#define THREADS 512    // 8 waves
#define GM      2      // m's per block
#define PMAX    32     // padded slots per m (worst-case inside count ~26)

// ws layout (floats):
//   ft[NN*CIN*BB]   : ft[n*128 + i*16 + b] = f[b][i][n]
//   lst[MM*PMAX*4]  : per slot float4 {zx, zy, bw, as_float(n)}
#define WS_FT 0
#define WS_L  (NN*CIN*BB)

// ---------------- kernel 1: feature transpose + inside-lists ----------------
__global__ __launch_bounds__(THREADS) void prep_kernel(
    const float* __restrict__ f,      // (B, CIN, NN)
    const float* __restrict__ locs,   // (MM, 2)
    const float* __restrict__ nodes,  // (NN, 2)
    const float* __restrict__ wq,     // (NN,)
    float* __restrict__ ws)
{
    const int blk = blockIdx.x;
    const int t   = threadIdx.x;

    if (blk < 100) {
        // transpose, read-coalesced: idx walks f linearly
        int idx = blk * 512 + t;              // = b*3200 + i*400 + n
        int b = idx / 3200;
        int r = idx - b * 3200;
        int i = r / 400;
        int n = r - i * 400;
        ws[WS_FT + n*128 + i*16 + b] = f[idx];
    } else {
        // inside-lists: 50 blocks x 8 waves, one m per wave
        const int lane = t & 63;
        const int w    = t >> 6;
        const int m    = (blk - 100) * 8 + w;
        const float2 y = ((const float2*)locs)[m];
        const float2* nd = (const float2*)nodes;
        float4* lst = (float4*)(ws + WS_L);
        int cnt = 0;
        for (int n0 = 0; n0 < NN; n0 += 64) {
            int n = n0 + lane;
            bool in = false;
            float zx = 0.f, zy = 0.f, bwv = 0.f;
            if (n < NN) {
                float2 x = nd[n];
                zx = y.x - x.x; zy = y.y - x.y;
                float s = zx*zx + zy*zy;
                float a = s * s;                    // ||z||^4
                if (a < (1.0f/625.0f)) {
                    in = true;
                    bwv = __expf(1.0f - 1.0f/(1.0f - 625.0f*a)) * wq[n];
                }
            }
            unsigned long long msk = __ballot(in);
            int idx = cnt + __popcll(msk & ((1ull << lane) - 1ull));
            if (in && idx < PMAX)
                lst[m*PMAX + idx] = make_float4(zx, zy, bwv, __int_as_float(n));
            cnt += __popcll(msk);
        }
        if (lane >= cnt && lane < PMAX)
            lst[m*PMAX + lane] = make_float4(0.f, 0.f, 0.f, __int_as_float(0));
    }
}

// ---------------- kernel 2: MLP eval + contraction ----------------
// grid = (MM/GM) * COUT = 200 * 8 = 1600 blocks
// block (pg, kg): m in [pg*2, pg*2+2), output channel o = kg.
// wave w (0..7): k = kg*8 + w  ->  o = kg, i = w.
// Phase B dot products use 4 independent FMA chains + tree combine, and
// 4 kv accumulators, to break the 64-cycle serial dependency chains that
// R5-R11 all carried (VALUBusy 26% = dep-stall-bound).
__global__ __launch_bounds__(THREADS, 4) void quadconv_kernel(
    const float* __restrict__ W1,     // (K, H, 2)
    const float* __restrict__ W2,     // (K, H, H)
    const float* __restrict__ W3,     // (K, 1, H)
    const float* __restrict__ ws,     // ft + lists
    float* __restrict__ out)          // (B, COUT, MM)
{
    __shared__ float s_w2[8*256];     // [k_local][oo*16+j]
    __shared__ float s_w1[8*32];      // [k_local][j*2+d]
    __shared__ float s_w3[8*16];      // [k_local][oo]
    __shared__ float s_kv[8*64];      // [wave][slot]
    __shared__ float s_part[8*32];    // [wave][g*16+b]
    __shared__ int   s_pn[64];        // node ids per slot

    const int t    = threadIdx.x;
    const int lane = t & 63;
    const int w    = __builtin_amdgcn_readfirstlane(t >> 6);
    const int pg   = blockIdx.x >> 3;
    const int kg   = blockIdx.x & 7;
    const int m0   = pg * GM;

    // ---- stage this block's 8 weight sets into LDS (one float4/thread) ----
    {
        const float4* W2v = (const float4*)(W2 + kg * 8 * 256);   // 512 float4
        ((float4*)s_w2)[t] = W2v[t];
        if (t < 64) ((float4*)s_w1)[t] = ((const float4*)(W1 + kg * 8 * 32))[t];
        if (t < 32) ((float4*)s_w3)[t] = ((const float4*)(W3 + kg * 8 * 16))[t];
    }

    // lane = slot (2 m's x 32 padded slots); one coalesced float4 per lane
    const float4 sv = ((const float4*)(ws + WS_L))[pg*64 + lane];
    if (t < 64) s_pn[t] = __float_as_int(sv.w);
    __syncthreads();

    // ---- Phase B: per-wave MLP from LDS weights, lane = slot ----
    {
        const float*  __restrict__ w1  = s_w1 + w * 32;
        const float*  __restrict__ w3  = s_w3 + w * 16;
        const float4* __restrict__ w2v = (const float4*)(s_w2 + w * 256);
        const float zx = sv.x, zy = sv.y, bw = sv.z;

        float h1[HH];
        #pragma unroll
        for (int j = 0; j < HH; ++j)
            h1[j] = __sinf(w1[2*j] * zx + w1[2*j + 1] * zy);

        float kva = 0.f, kvb = 0.f, kvc = 0.f, kvd = 0.f;
        #pragma unroll
        for (int oo = 0; oo < HH; ++oo) {
            float4 r0 = w2v[oo*4+0], r1 = w2v[oo*4+1],
                   r2 = w2v[oo*4+2], r3 = w2v[oo*4+3];
            // 4 independent 4-FMA chains, then 2-level tree combine
            float d0 = r0.x*h1[0]  + r0.y*h1[1]  + r0.z*h1[2]  + r0.w*h1[3];
            float d1 = r1.x*h1[4]  + r1.y*h1[5]  + r1.z*h1[6]  + r1.w*h1[7];
            float d2 = r2.x*h1[8]  + r2.y*h1[9]  + r2.z*h1[10] + r2.w*h1[11];
            float d3 = r3.x*h1[12] + r3.y*h1[13] + r3.z*h1[14] + r3.w*h1[15];
            float ss = __sinf((d0 + d1) + (d2 + d3));
            float term = w3[oo] * ss;
            if      ((oo & 3) == 0) kva += term;
            else if ((oo & 3) == 1) kvb += term;
            else if ((oo & 3) == 2) kvc += term;
            else                    kvd += term;
        }
        s_kv[w*64 + lane] = ((kva + kvb) + (kvc + kvd)) * bw;
    }
    // no block barrier: phase C reads only this wave's s_kv row (lgkmcnt
    // dependency handled by compiler); s_pn was synced at the first barrier.

    // ---- Phase C: contraction on transposed features (hoisted gathers) ----
    {
        const int b    = lane & 15;
        const int g    = (lane >> 4) & 1;
        const int half = lane >> 5;
        const int sl0  = g*PMAX + half*(PMAX/2);
        const float* __restrict__ ftp = ws + WS_FT;

        int nn[PMAX/2];
        #pragma unroll
        for (int jj = 0; jj < PMAX/2; ++jj)
            nn[jj] = s_pn[sl0 + jj];
        float fv[PMAX/2];
        #pragma unroll
        for (int jj = 0; jj < PMAX/2; ++jj)
            fv[jj] = ftp[nn[jj]*128 + w*16 + b];     // i = w
        // 4 independent accumulation chains
        float a0 = 0.f, a1 = 0.f, a2 = 0.f, a3 = 0.f;
        #pragma unroll
        for (int jj = 0; jj < PMAX/2; jj += 4) {
            a0 += s_kv[w*64 + sl0 + jj    ] * fv[jj];
            a1 += s_kv[w*64 + sl0 + jj + 1] * fv[jj + 1];
            a2 += s_kv[w*64 + sl0 + jj + 2] * fv[jj + 2];
            a3 += s_kv[w*64 + sl0 + jj + 3] * fv[jj + 3];
        }
        float acc = (a0 + a1) + (a2 + a3);

        acc += __shfl_xor(acc, 32);       // combine the two halves
        if (half == 0)
            s_part[w*32 + lane] = acc;    // lane = g*16 + b
    }
    __syncthreads();

    // ---- Final: sum over i (=wave) and store ----
    if (t < 32) {
        const int b = t & 15, g = t >> 4;
        float v = 0.f;
        #pragma unroll
        for (int ww = 0; ww < 8; ++ww)
            v += s_part[ww*32 + t];
        out[b * (COUT*MM) + kg * MM + (m0 + g)] = v;
    }
}

extern "C" void kernel_launch(void* const* d_in, const int* in_sizes, int n_in,
                              void* d_out, int out_size, void* d_ws, size_t ws_size,
                              hipStream_t stream) {
    const float* f     = (const float*)d_in[0];
    const float* W1    = (const float*)d_in[1];
    const float* W2    = (const float*)d_in[2];
    const float* W3    = (const float*)d_in[3];
    const float* locs  = (const float*)d_in[4];
    const float* nodes = (const float*)d_in[5];
    const float* wq    = (const float*)d_in[6];
    float* out = (float*)d_out;
    float* ws  = (float*)d_ws;

    prep_kernel<<<dim3(150), dim3(THREADS), 0, stream>>>(f, locs, nodes, wq, ws);
    quadconv_kernel<<<dim3((MM/GM) * COUT), dim3(THREADS), 0, stream>>>(
        W1, W2, W3, ws, out);
}